// Round 5
// baseline (1127.388 us; speedup 1.0000x reference)
//
#include <hip/hip_runtime.h>

// Sizes fixed by the problem
#define Bb   64
#define Ee   2048
#define Tt   64
#define Gg   4096
#define Ii   256
#define Hh   32
#define Dd   64

using f32x4_t  = __attribute__((ext_vector_type(4))) float;
using bf16x8_t = __attribute__((ext_vector_type(8))) __bf16;

__device__ __forceinline__ unsigned short f2bf(float f) {
  unsigned u = __float_as_uint(f);
  u += 0x7FFFu + ((u >> 16) & 1u);          // RNE
  return (unsigned short)(u >> 16);
}
__device__ __forceinline__ float ldkv(float v) { return v; }
__device__ __forceinline__ float ldkv(unsigned short v) {
  return __uint_as_float(((unsigned)v) << 16);
}
__device__ __forceinline__ float gelu_f(float x) {
  return 0.5f * x * (1.0f + erff(x * 0.70710678118654752f));
}
// async global->LDS, 16B per lane; LDS dst = wave-uniform base + lane*16
__device__ __forceinline__ void gld16(const void* g, void* l) {
  __builtin_amdgcn_global_load_lds(
      (const __attribute__((address_space(1))) unsigned int*)g,
      (__attribute__((address_space(3))) unsigned int*)l, 16, 0, 0);
}

template <typename T> __device__ __forceinline__ float4 ld4(const T* p);
template <> __device__ __forceinline__ float4 ld4<float>(const float* p) {
  return *(const float4*)p;
}
template <> __device__ __forceinline__ float4 ld4<unsigned short>(const unsigned short* p) {
  ushort4 u = *(const ushort4*)p;
  return make_float4(ldkv(u.x), ldkv(u.y), ldkv(u.z), ldkv(u.w));
}

// ---------------- prep: enc->bf16 + transpose k_ca,v_ca -> [N][K] bf16, one dispatch ----------------
__global__ void prep_k(const float* __restrict__ enc, unsigned short* __restrict__ ebf,
                       const float* __restrict__ Wk, unsigned short* __restrict__ kt,
                       const float* __restrict__ Wv, unsigned short* __restrict__ vt) {
  int bid = blockIdx.x;
  if (bid < 2048) {                      // transpose tiles: 1024 for kt, 1024 for vt
    const float* W = (bid < 1024) ? Wk : Wv;
    unsigned short* Wt = (bid < 1024) ? kt : vt;
    int ti = bid & 1023;
    __shared__ unsigned short tile[64][65];
    int k0 = (ti & 31) * 64, n0 = (ti >> 5) * 64;
    int c = threadIdx.x & 63;
    int r4 = threadIdx.x >> 6;
    #pragma unroll
    for (int i = 0; i < 16; i++) {
      int r = r4 + i * 4;
      tile[r][c] = f2bf(W[(long)(k0 + r) * Ee + n0 + c]);
    }
    __syncthreads();
    #pragma unroll
    for (int i = 0; i < 16; i++) {
      int r = r4 + i * 4;
      Wt[(long)(n0 + r) * Ee + k0 + c] = tile[c][r];
    }
  } else {                               // conv: 2048 blocks, grid-stride
    long i = (long)(bid - 2048) * 256 + threadIdx.x;
    const long n4 = (long)Bb * Tt * Ee / 4;
    for (; i < n4; i += 2048L * 256) {
      float4 f = ((const float4*)enc)[i];
      ushort4 u;
      u.x = f2bf(f.x); u.y = f2bf(f.y); u.z = f2bf(f.z); u.w = f2bf(f.w);
      *(ushort4*)(ebf + i * 4) = u;
    }
  }
}

// ---------------- fused dual-GEMM: C0 = A@B0^T, C1 = A@B1^T (bf16 MFMA, global_load_lds) ----------------
// A [M][K], B*t [N][K] bf16.  Block: 128m x 64n for BOTH outputs; wave w: output w>>1, m-half w&1.
// LDS layout k-grouped so DMA dst (base+lane*16) == frag-read layout (16B/lane stride, conflict-free):
//   As[kg*1024 + m*8 + k7], Bs[out][kg*512 + n*8 + k7]  (ushort units)
__global__ __launch_bounds__(256)
void gemm2_k(const unsigned short* __restrict__ A,
             const unsigned short* __restrict__ B0t, const unsigned short* __restrict__ B1t,
             unsigned short* __restrict__ C0, unsigned short* __restrict__ C1,
             int M, int N, int K) {
  __shared__ __align__(16) unsigned short As[4096];
  __shared__ __align__(16) unsigned short Bs[2][2048];
  const int m0 = blockIdx.x * 128;
  const int n0 = blockIdx.y * 64;
  const int tid  = threadIdx.x;
  const int lane = tid & 63;
  const int wave = tid >> 6;
  const int out  = wave >> 1;
  const int wm   = (wave & 1) * 64;
  const int fr = lane & 15;
  const int fq = lane >> 4;

  f32x4_t acc[4][4];
  const f32x4_t zero = {0.f, 0.f, 0.f, 0.f};
  #pragma unroll
  for (int i = 0; i < 4; i++)
    #pragma unroll
    for (int j = 0; j < 4; j++) acc[i][j] = zero;

  for (int k0 = 0; k0 < K; k0 += 32) {
    __syncthreads();                     // previous iter's ds_reads done
    // A tile 128x32: 8 lane-chunks; wave stages chunks {wave, wave+4}
    #pragma unroll
    for (int p = 0; p < 2; p++) {
      int c = p * 4 + wave;
      int kg = c >> 1, mh = c & 1;
      gld16(A + (long)(m0 + mh * 64 + lane) * K + k0 + kg * 8,
            &As[kg * 1024 + mh * 512]);
    }
    // B tiles 64x32 each: wave stages k-group = wave for both B's
    gld16(B0t + (long)(n0 + lane) * K + k0 + wave * 8, &Bs[0][wave * 512]);
    gld16(B1t + (long)(n0 + lane) * K + k0 + wave * 8, &Bs[1][wave * 512]);
    __syncthreads();                     // drains vmcnt (DMA complete)

    bf16x8_t af[4], bf_[4];
    #pragma unroll
    for (int ms = 0; ms < 4; ms++)
      af[ms] = __builtin_bit_cast(bf16x8_t,
               *(const uint4*)&As[fq * 1024 + (wm + ms * 16 + fr) * 8]);
    #pragma unroll
    for (int ns = 0; ns < 4; ns++)
      bf_[ns] = __builtin_bit_cast(bf16x8_t,
               *(const uint4*)&Bs[out][fq * 512 + (ns * 16 + fr) * 8]);
    #pragma unroll
    for (int ms = 0; ms < 4; ms++)
      #pragma unroll
      for (int ns = 0; ns < 4; ns++)
        acc[ms][ns] = __builtin_amdgcn_mfma_f32_16x16x32_bf16(af[ms], bf_[ns], acc[ms][ns], 0, 0, 0);
  }

  unsigned short* C = out ? C1 : C0;
  #pragma unroll
  for (int ms = 0; ms < 4; ms++) {
    #pragma unroll
    for (int ns = 0; ns < 4; ns++) {
      int row = m0 + wm + ms * 16 + fq * 4;
      int col = n0 + ns * 16 + fr;
      #pragma unroll
      for (int r = 0; r < 4; r++)
        C[(long)(row + r) * N + col] = f2bf(acc[ms][ns][r]);
    }
  }
}

// ---------------- plain layer norm (bias only): one-pass, 1 float4/thread ----------------
__global__ void ln_k(const float4* __restrict__ in1, const float* __restrict__ bias,
                     float4* __restrict__ out1) {
  const int row = blockIdx.x, tid = threadIdx.x;
  const int C = blockDim.x * 4;
  const long base = (long)row * blockDim.x + tid;

  float4 p = in1[base];
  float s  = p.x + p.y + p.z + p.w;
  float s2 = p.x * p.x + p.y * p.y + p.z * p.z + p.w * p.w;

  __shared__ float rs[16], rs2[16];
  int lane = tid & 63, w = tid >> 6;
  #pragma unroll
  for (int o = 32; o; o >>= 1) { s += __shfl_down(s, o, 64); s2 += __shfl_down(s2, o, 64); }
  if (lane == 0) { rs[w] = s; rs2[w] = s2; }
  __syncthreads();
  if (tid == 0) {
    float ts = 0.f, ts2 = 0.f;
    int nw = blockDim.x >> 6;
    for (int i = 0; i < nw; i++) { ts += rs[i]; ts2 += rs2[i]; }
    float mu = ts / C;
    rs[0]  = mu;
    rs2[0] = rsqrtf(ts2 / C - mu * mu + 1e-6f);
  }
  __syncthreads();
  const float mu = rs[0], rstd = rs2[0];
  float4 b4 = ((const float4*)bias)[tid];
  float4 o;
  o.x = (p.x - mu) * rstd + b4.x; o.y = (p.y - mu) * rstd + b4.y;
  o.z = (p.z - mu) * rstd + b4.z; o.w = (p.w - mu) * rstd + b4.w;
  out1[base] = o;
}

// ---------------- fused: reduce KB partials -> LN(*s1+b1)+res -> (out_res[,out_res2]) -> LN(+b2) -> out_ln ----------------
template <bool DUAL>
__global__ void redln2_k(const float4* __restrict__ P, long ks4, int KB,
                         const float* __restrict__ s1, const float* __restrict__ b1,
                         const float4* __restrict__ res, const float* __restrict__ b2,
                         float4* __restrict__ o_res, float4* __restrict__ o_res2,
                         float4* __restrict__ o_ln) {
  const int row = blockIdx.x, tid = threadIdx.x;
  const int C = blockDim.x * 4;
  const long base = (long)row * blockDim.x + tid;

  float4 p = make_float4(0.f, 0.f, 0.f, 0.f);
  for (int k = 0; k < KB; k++) {
    float4 q = P[(long)k * ks4 + base];
    p.x += q.x; p.y += q.y; p.z += q.z; p.w += q.w;
  }

  __shared__ float rs[16], rs2[16];
  const int lane = tid & 63, w = tid >> 6;
  const int nw = blockDim.x >> 6;
  // --- LN1 stats ---
  float s = p.x + p.y + p.z + p.w;
  float s2 = p.x * p.x + p.y * p.y + p.z * p.z + p.w * p.w;
  #pragma unroll
  for (int o = 32; o; o >>= 1) { s += __shfl_down(s, o, 64); s2 += __shfl_down(s2, o, 64); }
  if (lane == 0) { rs[w] = s; rs2[w] = s2; }
  __syncthreads();
  if (tid == 0) {
    float ts = 0.f, ts2 = 0.f;
    for (int i = 0; i < nw; i++) { ts += rs[i]; ts2 += rs2[i]; }
    float mu = ts / C;
    rs[0] = mu; rs2[0] = rsqrtf(ts2 / C - mu * mu + 1e-6f);
  }
  __syncthreads();
  const float mu1 = rs[0], rstd1 = rs2[0];
  float4 sc = ((const float4*)s1)[tid];
  float4 bb = ((const float4*)b1)[tid];
  float4 r4 = res[base];
  float4 y;
  y.x = (p.x - mu1) * rstd1 * sc.x + bb.x + r4.x;
  y.y = (p.y - mu1) * rstd1 * sc.y + bb.y + r4.y;
  y.z = (p.z - mu1) * rstd1 * sc.z + bb.z + r4.z;
  y.w = (p.w - mu1) * rstd1 * sc.w + bb.w + r4.w;
  o_res[base] = y;
  if (DUAL) o_res2[base] = y;
  // --- LN2 stats on y ---
  s = y.x + y.y + y.z + y.w;
  s2 = y.x * y.x + y.y * y.y + y.z * y.z + y.w * y.w;
  #pragma unroll
  for (int o = 32; o; o >>= 1) { s += __shfl_down(s, o, 64); s2 += __shfl_down(s2, o, 64); }
  __syncthreads();
  if (lane == 0) { rs[w] = s; rs2[w] = s2; }
  __syncthreads();
  if (tid == 0) {
    float ts = 0.f, ts2 = 0.f;
    for (int i = 0; i < nw; i++) { ts += rs[i]; ts2 += rs2[i]; }
    float mu = ts / C;
    rs[0] = mu; rs2[0] = rsqrtf(ts2 / C - mu * mu + 1e-6f);
  }
  __syncthreads();
  const float mu2 = rs[0], rstd2 = rs2[0];
  float4 b24 = ((const float4*)b2)[tid];
  float4 z;
  z.x = (y.x - mu2) * rstd2 + b24.x; z.y = (y.y - mu2) * rstd2 + b24.y;
  z.z = (y.z - mu2) * rstd2 + b24.z; z.w = (y.w - mu2) * rstd2 + b24.w;
  o_ln[base] = z;
}

// ---------------- fused: reduce w0,v1 partials -> gelu(w)*v -> LN*s+b -> out ----------------
__global__ void redln_gelu_k(const float4* __restrict__ P, long ks4, int KB, long off2,
                             const float* __restrict__ scale, const float* __restrict__ bias,
                             float4* __restrict__ out) {
  const int row = blockIdx.x, tid = threadIdx.x;
  const int C = blockDim.x * 4;
  const long base = (long)row * blockDim.x + tid;

  float4 a = make_float4(0.f, 0.f, 0.f, 0.f), b = a;
  for (int k = 0; k < KB; k++) {
    float4 q = P[(long)k * ks4 + base];
    a.x += q.x; a.y += q.y; a.z += q.z; a.w += q.w;
    float4 r = P[(long)k * ks4 + off2 + base];
    b.x += r.x; b.y += r.y; b.z += r.z; b.w += r.w;
  }
  float4 p;
  p.x = gelu_f(a.x) * b.x; p.y = gelu_f(a.y) * b.y;
  p.z = gelu_f(a.z) * b.z; p.w = gelu_f(a.w) * b.w;

  float s  = p.x + p.y + p.z + p.w;
  float s2 = p.x * p.x + p.y * p.y + p.z * p.z + p.w * p.w;
  __shared__ float rs[16], rs2[16];
  int lane = tid & 63, w = tid >> 6;
  #pragma unroll
  for (int o = 32; o; o >>= 1) { s += __shfl_down(s, o, 64); s2 += __shfl_down(s2, o, 64); }
  if (lane == 0) { rs[w] = s; rs2[w] = s2; }
  __syncthreads();
  if (tid == 0) {
    float ts = 0.f, ts2 = 0.f;
    int nw = blockDim.x >> 6;
    for (int i = 0; i < nw; i++) { ts += rs[i]; ts2 += rs2[i]; }
    float mu = ts / C;
    rs[0] = mu; rs2[0] = rsqrtf(ts2 / C - mu * mu + 1e-6f);
  }
  __syncthreads();
  const float mu = rs[0], rstd = rs2[0];
  float4 sc4 = ((const float4*)scale)[tid];
  float4 b4  = ((const float4*)bias)[tid];
  float4 o;
  o.x = (p.x - mu) * rstd * sc4.x + b4.x; o.y = (p.y - mu) * rstd * sc4.y + b4.y;
  o.z = (p.z - mu) * rstd * sc4.z + b4.z; o.w = (p.w - mu) * rstd * sc4.w + b4.w;
  out[base] = o;
}

// ---------------- M=64 projection, atomic-free split-K ----------------
template <int NW>
__global__ __launch_bounds__(256)
void proj_k(const float* __restrict__ X,
            const float* __restrict__ W0, const float* __restrict__ W1,
            const float* __restrict__ W2,
            float* __restrict__ P, int K, int N) {
  __shared__ float Xs[64 * 64];
  const int nq = threadIdx.x & 31;
  const int m0 = (threadIdx.x >> 5) * 8;
  const int n  = blockIdx.x * 128 + nq * 4;
  const int kbase = blockIdx.y * 128;

  f32x4_t acc[NW][8];
  #pragma unroll
  for (int wsel = 0; wsel < NW; wsel++)
    #pragma unroll
    for (int i = 0; i < 8; i++) acc[wsel][i] = (f32x4_t){0.f, 0.f, 0.f, 0.f};

  for (int k0 = kbase; k0 < kbase + 128; k0 += 64) {
    __syncthreads();
    #pragma unroll
    for (int j = 0; j < 16; j++) {
      int e = threadIdx.x + j * 256;        // e = m*64 + kk  (coalesced)
      Xs[e] = X[(long)(e >> 6) * K + k0 + (e & 63)];
    }
    __syncthreads();
    #pragma unroll 4
    for (int kk = 0; kk < 64; kk++) {
      const long wrow = (long)(k0 + kk) * N + n;
      f32x4_t w4[NW];
      w4[0] = *(const f32x4_t*)(W0 + wrow);
      if (NW > 1) w4[1] = *(const f32x4_t*)(W1 + wrow);
      if (NW > 2) w4[2] = *(const f32x4_t*)(W2 + wrow);
      #pragma unroll
      for (int i = 0; i < 8; i++) {
        float xm = Xs[(m0 + i) * 64 + kk];
        #pragma unroll
        for (int wsel = 0; wsel < NW; wsel++) acc[wsel][i] += xm * w4[wsel];
      }
    }
  }
  float* base = P + (long)blockIdx.y * ((long)NW * 64 * N);
  #pragma unroll
  for (int wsel = 0; wsel < NW; wsel++)
    #pragma unroll
    for (int i = 0; i < 8; i++)
      *(f32x4_t*)(base + ((long)wsel * 64 + m0 + i) * N + n) = acc[wsel][i];
}

// ---------------- split-K reduce (fc2): out_dec += sum_k P ----------------
__global__ void reduce_acc_k(const float4* __restrict__ P, float4* __restrict__ Y,
                             int KB, long n4) {
  long i = (long)blockIdx.x * blockDim.x + threadIdx.x;
  if (i >= n4) return;
  float4 s = Y[i];
  for (int k = 0; k < KB; k++) {
    float4 p = P[(long)k * n4 + i];
    s.x += p.x; s.y += p.y; s.z += p.z; s.w += p.w;
  }
  Y[i] = s;
}

// ---------------- state copy + KV update from partials + q reduce, one dispatch ----------------
// blocks [0,128): qb[i] = sum_k qkv-partials(w=0); blocks [128,..): grid-stride state copy,
// t-row rows take k/v from reduced partials (w=1/2).
__global__ void copyred_k(const float4* __restrict__ src, float4* __restrict__ dst,
                          const float4* __restrict__ arena, float4* __restrict__ qb,
                          const int* __restrict__ tokp) {
  const int t = *tokp;
  const int bid = blockIdx.x;
  if (bid < 128) {
    long i = (long)bid * 256 + threadIdx.x;       // 32768 = 64*2048/4
    float4 s = make_float4(0.f, 0.f, 0.f, 0.f);
    for (int k = 0; k < 16; k++) {
      float4 p = arena[(long)k * 98304 + i];      // w=0 (q)
      s.x += p.x; s.y += p.y; s.z += p.z; s.w += p.w;
    }
    qb[i] = s;
    return;
  }
  const long n4 = (long)128 * Ii * (Ee / 4);
  long i = (long)(bid - 128) * 256 + threadIdx.x;
  const long stride = (long)(gridDim.x - 128) * 256;
  for (; i < n4; i += stride) {
    long row = i >> 9;
    int tt = (int)(row & (Ii - 1));
    float4 v;
    if (tt == t) {                                 // wave-uniform
      int bh  = (int)(row >> 8);                   // 0..127
      int col = (int)(i & 511);
      long off = (bh < Bb) ? (32768L + (long)bh * 512 + col)          // k (w=1)
                           : (65536L + (long)(bh - Bb) * 512 + col);  // v (w=2)
      v = make_float4(0.f, 0.f, 0.f, 0.f);
      for (int k = 0; k < 16; k++) {
        float4 p = arena[(long)k * 98304 + off];
        v.x += p.x; v.y += p.y; v.z += p.z; v.w += p.w;
      }
    } else {
      v = src[i];
    }
    dst[i] = v;
  }
}

// ---------------- attention (Q=1): one wave per (b,h); optional inline q-reduce ----------------
template <typename KVT>
__global__ void attn_k(const float* __restrict__ Q, const float* __restrict__ qred, long qks,
                       const KVT* __restrict__ Kc, const KVT* __restrict__ Vc,
                       float* __restrict__ O,
                       const int* __restrict__ tokp, const int* __restrict__ maskp,
                       int L, long bstride, float scale) {
  const int b = blockIdx.x, h = blockIdx.y;
  const int lane = threadIdx.x;                 // 64 threads = 1 wave
  __shared__ float sc[256];
  __shared__ float sq[64];
  const int n = tokp ? (*tokp + 1) : L;

  const float* qp;
  if (qred) {
    float s = 0.f;
    long e = (long)b * Ee + h * Dd + lane;
    for (int k = 0; k < 16; k++) s += qred[(long)k * qks + e];
    sq[lane] = s;
    __syncthreads();
    qp = sq;
  } else {
    qp = Q + (long)b * Ee + h * Dd;             // wave-uniform -> scalar loads
  }

  float mx = -3.0e38f;
  for (int pos = lane; pos < n; pos += 64) {
    bool valid = maskp ? (maskp[(long)b * L + pos] != 0) : true;
    float s = -1.0e30f;
    if (valid) {
      const KVT* kr = Kc + (long)b * bstride + (long)pos * Ee + h * Dd;
      float acc = 0.f;
      #pragma unroll
      for (int j = 0; j < 16; j++) {
        float4 kv = ld4(kr + j * 4);
        acc += qp[j*4+0]*kv.x + qp[j*4+1]*kv.y + qp[j*4+2]*kv.z + qp[j*4+3]*kv.w;
      }
      s = acc * scale;
    }
    sc[pos] = s;
    mx = fmaxf(mx, s);
  }
  __syncthreads();
  #pragma unroll
  for (int o = 32; o; o >>= 1) mx = fmaxf(mx, __shfl_down(mx, o, 64));
  mx = __shfl(mx, 0, 64);

  float sum = 0.f;
  for (int pos = lane; pos < n; pos += 64) {
    float e = expf(sc[pos] - mx);
    sc[pos] = e;                                // masked positions -> exactly 0
    sum += e;
  }
  __syncthreads();
  #pragma unroll
  for (int o = 32; o; o >>= 1) sum += __shfl_down(sum, o, 64);
  sum = __shfl(sum, 0, 64);
  const float inv = 1.0f / sum;

  const KVT* vbase = Vc + (long)b * bstride + h * Dd + lane;
  float acc = 0.f;
  int pos = 0;
  for (; pos + 8 <= n; pos += 8) {
    #pragma unroll
    for (int u = 0; u < 8; u++)
      acc += sc[pos + u] * ldkv(vbase[(long)(pos + u) * Ee]);
  }
  for (; pos < n; pos++) acc += sc[pos] * ldkv(vbase[(long)pos * Ee]);
  O[(long)b * Ee + h * Dd + lane] = acc * inv;
}

extern "C" void kernel_launch(void* const* d_in, const int* in_sizes, int n_in,
                              void* d_out, int out_size, void* d_ws, size_t ws_size,
                              hipStream_t stream) {
  const float* dec    = (const float*)d_in[0];
  const float* enc    = (const float*)d_in[1];
  const float* astate = (const float*)d_in[2];
  const int*   amask  = (const int*)d_in[3];
  const int*   tokp   = (const int*)d_in[4];
  const float* ln_pre_sa_b = (const float*)d_in[5];
  const float* q_sa = (const float*)d_in[6];
  const float* k_sa = (const float*)d_in[7];
  const float* v_sa = (const float*)d_in[8];
  const float* o_sa = (const float*)d_in[9];
  const float* ln_sa_s = (const float*)d_in[10];
  const float* ln_sa_b = (const float*)d_in[11];
  const float* ln_pre_ca_b = (const float*)d_in[12];
  const float* q_ca = (const float*)d_in[13];
  const float* k_ca = (const float*)d_in[14];
  const float* v_ca = (const float*)d_in[15];
  const float* o_ca = (const float*)d_in[16];
  const float* ln_ca_s = (const float*)d_in[17];
  const float* ln_ca_b = (const float*)d_in[18];
  const float* glu_ln0_b = (const float*)d_in[19];
  const float* fc0 = (const float*)d_in[20];
  const float* fc1 = (const float*)d_in[21];
  const float* glu_ln1_s = (const float*)d_in[22];
  const float* glu_ln1_b = (const float*)d_in[23];
  const float* fc2 = (const float*)d_in[24];

  float* out_dec   = (float*)d_out;
  float* out_state = out_dec + (long)Bb * Ee;

  // ---- workspace carve ----
  float* x1  = (float*)d_ws;            // 64*2048 each
  float* qb  = x1  + 131072;
  float* ab  = qb  + 131072;
  float* ds2 = ab  + 131072;
  float* x3  = ds2 + 131072;
  float* cb  = x3  + 131072;
  float* ds3 = cb  + 131072;
  float* zb  = ds3 + 131072;
  float* wvn = zb  + 131072;            // 64*4096
  unsigned short* ebf = (unsigned short*)(wvn + 262144);  // 4096*2048 bf16
  unsigned short* kt  = ebf + 8388608;                    // 2048*2048 bf16 [N][K]
  unsigned short* vt  = kt  + 4194304;
  unsigned short* ekb = vt  + 4194304;                    // 4096*2048 bf16
  unsigned short* evb = ekb + 8388608;
  float* arena = (float*)(evb + 8388608);                 // split-K partials, <=33.6 MB

  // prep (conv + both weight transposes) and the fused dual-GEMM
  prep_k<<<4096, 256, 0, stream>>>(enc, ebf, k_ca, kt, v_ca, vt);
  gemm2_k<<<dim3(32, 32), 256, 0, stream>>>(ebf, kt, vt, ekb, evb, 4096, Ee, Ee);

  // --- self-attention block ---
  ln_k<<<Bb, 512, 0, stream>>>((const float4*)dec, ln_pre_sa_b, (float4*)x1);
  proj_k<3><<<dim3(16, 16), 256, 0, stream>>>(x1, q_sa, k_sa, v_sa, arena, Ee, Ee);
  copyred_k<<<8320, 256, 0, stream>>>((const float4*)astate, (float4*)out_state,
                                      (const float4*)arena, (float4*)qb, tokp);
  attn_k<float><<<dim3(Bb, Hh), 64, 0, stream>>>(qb, nullptr, 0, out_state,
      out_state + (long)Bb * Ii * Ee, ab, tokp, nullptr, Ii, (long)Ii * Ee, 0.125f);
  proj_k<1><<<dim3(16, 16), 256, 0, stream>>>(ab, o_sa, nullptr, nullptr, arena, Ee, Ee);
  redln2_k<false><<<Bb, 512, 0, stream>>>((const float4*)arena, 32768, 16,
      ln_sa_s, ln_sa_b, (const float4*)dec, ln_pre_ca_b,
      (float4*)ds2, nullptr, (float4*)x3);

  // --- cross-attention block ---
  proj_k<1><<<dim3(16, 16), 256, 0, stream>>>(x3, q_ca, nullptr, nullptr, arena, Ee, Ee);
  attn_k<unsigned short><<<dim3(Bb, Hh), 64, 0, stream>>>(nullptr, arena, 131072,
      ekb, evb, cb, nullptr, amask, Tt, (long)Tt * Ee, 0.125f);
  proj_k<1><<<dim3(16, 16), 256, 0, stream>>>(cb, o_ca, nullptr, nullptr, arena, Ee, Ee);
  redln2_k<true><<<Bb, 512, 0, stream>>>((const float4*)arena, 32768, 16,
      ln_ca_s, ln_ca_b, (const float4*)ds2, glu_ln0_b,
      (float4*)ds3, (float4*)out_dec, (float4*)zb);

  // --- GLU block ---
  proj_k<2><<<dim3(32, 16), 256, 0, stream>>>(zb, fc0, fc1, nullptr, arena, Ee, Gg);
  redln_gelu_k<<<Bb, 1024, 0, stream>>>((const float4*)arena, 131072, 16, 65536,
      glu_ln1_s, glu_ln1_b, (float4*)wvn);
  proj_k<1><<<dim3(16, 32), 256, 0, stream>>>(wvn, fc2, nullptr, nullptr, arena, Gg, Ee);
  reduce_acc_k<<<128, 256, 0, stream>>>((const float4*)arena, (float4*)out_dec, 32, 32768);
}